// Round 6
// baseline (254.747 us; speedup 1.0000x reference)
//
#include <hip/hip_runtime.h>

// RWKV-7 DPLR single-step decode: B=64, H=32, K=V=128, fp32.
// v7: 4-way COLUMN split -> one wave per (bh, 32-col quarter).
// Round-5 evidence: barrier-free v6 still hit the 83us wall at 18%
// occupancy / 8 waves/CU, delivering only ~4.8 B/cyc/CU -> ~4 KB in
// flight per CU: MLP-starved, not traffic- or coupling-limited.
// Columns of H are independent (s,t are per-column row-reductions;
// alpha/beta recomputed per wave), so splitting columns 4x multiplies
// independent waves to 8192 (32/CU) with ZERO cross-wave coupling and
// zero barriers. No register-keep: lean VGPR -> 6 waves/SIMD cap.
// Phase-2 re-read uses NORMAL loads (v6's nt loads appear to have
// bypassed L3: FETCH jumped 68->113 MB); Ht stores stay nontemporal.
//
// Geometry per wave: 128 rows x 32 cols. lane = rg*8 + l8;
//   rg = lane>>3 (row group 0..7), l8 = lane&7 (column sub-block).
//   Wave-load m covers rows m*8+rg, cols c4..c4+3  (8 x 128B segments).
//   Lane's rows: r = m*8 + rg, m = 0..15.
// Per-row scalars staged in wave-private LDS at [r&7][r>>3] so the
// phase loops read them as broadcast f32x4 chunks. Same-wave RAW on
// LDS needs no barrier (lgkmcnt-ordered by compiler).

#define KD 128
#define VD 128
#define BH_TOTAL 2048        // B*H
#define WPB 4                // waves per block = column quarters
#define NBLK BH_TOTAL        // one block per bh; wave w = quarter w

typedef float f32x4 __attribute__((ext_vector_type(4)));

__global__ __launch_bounds__(256, 6) void dplr_decode_colsplit_kernel(
    const float* __restrict__ q_,  const float* __restrict__ k_,
    const float* __restrict__ v_,  const float* __restrict__ a_,
    const float* __restrict__ b_,  const float* __restrict__ gk_,
    const float* __restrict__ h0_, float* __restrict__ out_)
{
    const int tid  = threadIdx.x;
    const int wid  = tid >> 6;           // column quarter 0..3
    const int lane = tid & 63;
    const int bh   = blockIdx.x;
    const int rg   = lane >> 3;          // row group 0..7
    const int l8   = lane & 7;           // col sub-block 0..7
    const int c4   = wid * 32 + l8 * 4;  // my column base

    const size_t vec_off = (size_t)bh * KD;
    const size_t h_off   = (size_t)bh * (KD * VD);

    // wave-private per-row scalar tables: value for row r at [r&7][r>>3]
    __shared__ float aL[WPB][8][16], qgL[WPB][8][16], gL[WPB][8][16],
                     bL[WPB][8][16], kL[WPB][8][16];

    // ---- stage per-(b,h) vectors (each lane: elements lane, lane+64) ----
    const float q_lo = q_[vec_off + lane],  q_hi = q_[vec_off + lane + 64];
    const float b_lo = b_[vec_off + lane],  b_hi = b_[vec_off + lane + 64];
    const float k_lo = k_[vec_off + lane],  k_hi = k_[vec_off + lane + 64];
    const float a_lo = a_[vec_off + lane],  a_hi = a_[vec_off + lane + 64];
    const float g_lo = expf(gk_[vec_off + lane]);
    const float g_hi = expf(gk_[vec_off + lane + 64]);

    {
        const int p  = lane & 7;         // row-group of element `lane`
        const int m0 = lane >> 3;        // chunk of element `lane`
        aL [wid][p][m0] = a_lo;        aL [wid][p][m0 + 8] = a_hi;
        qgL[wid][p][m0] = q_lo * g_lo; qgL[wid][p][m0 + 8] = q_hi * g_hi;
        gL [wid][p][m0] = g_lo;        gL [wid][p][m0 + 8] = g_hi;
        bL [wid][p][m0] = b_lo;        bL [wid][p][m0 + 8] = b_hi;
        kL [wid][p][m0] = k_lo;        kL [wid][p][m0 + 8] = k_hi;
    }

    // ---- alpha = q.b, beta = q.k : butterfly, every lane gets totals ----
    float alpha = q_lo * b_lo + q_hi * b_hi;
    float beta  = q_lo * k_lo + q_hi * k_hi;
#pragma unroll
    for (int o = 32; o > 0; o >>= 1) {
        alpha += __shfl_xor(alpha, o, 64);
        beta  += __shfl_xor(beta,  o, 64);
    }

    // v for my 4 columns
    const f32x4 v4 = *(const f32x4*)(v_ + vec_off + c4);

    // my H element for chunk m: row m*8+rg, cols c4.. -> hp + m*8*VD
    const float* hp = h0_ + h_off + (size_t)rg * VD + c4;

    // ---- phase 1: s/t partials over my 16 rows ----
    f32x4 sp = {0.f, 0.f, 0.f, 0.f};
    f32x4 tp = {0.f, 0.f, 0.f, 0.f};
#pragma unroll
    for (int mb = 0; mb < 4; ++mb) {
        const f32x4 av = *(const f32x4*)&aL [wid][rg][mb * 4];
        const f32x4 qv = *(const f32x4*)&qgL[wid][rg][mb * 4];
#pragma unroll
        for (int e = 0; e < 4; ++e) {
            const int m = mb * 4 + e;
            const f32x4 h = *(const f32x4*)(hp + (size_t)m * (8 * VD));
            sp += av[e] * h;
            tp += qv[e] * h;
        }
    }

    // ---- combine across the 8 row-groups (xor masks 8,16,32) ----
    f32x4 s4, t4;
#pragma unroll
    for (int e = 0; e < 4; ++e) {
        float x = sp[e];
        x += __shfl_xor(x,  8, 64);
        x += __shfl_xor(x, 16, 64);
        x += __shfl_xor(x, 32, 64);
        s4[e] = x;
        float y = tp[e];
        y += __shfl_xor(y,  8, 64);
        y += __shfl_xor(y, 16, 64);
        y += __shfl_xor(y, 32, 64);
        t4[e] = y;
    }

    // ---- o for my 4 columns (row-group 0 lanes write) ----
    if (rg == 0) {
        const f32x4 o4 = t4 + alpha * s4 + beta * v4;
        *(f32x4*)(out_ + (size_t)bh * VD + c4) = o4;
    }

    // ---- phase 2: Ht = g*H + b s^T + k v^T over my 16 rows ----
    float* op = out_ + (size_t)BH_TOTAL * VD + h_off + (size_t)rg * VD + c4;
#pragma unroll
    for (int mb = 0; mb < 4; ++mb) {
        const f32x4 gv = *(const f32x4*)&gL[wid][rg][mb * 4];
        const f32x4 bv = *(const f32x4*)&bL[wid][rg][mb * 4];
        const f32x4 kv = *(const f32x4*)&kL[wid][rg][mb * 4];
#pragma unroll
        for (int e = 0; e < 4; ++e) {
            const int m = mb * 4 + e;
            const f32x4 h = *(const f32x4*)(hp + (size_t)m * (8 * VD));
            const f32x4 o4 = gv[e] * h + bv[e] * s4 + kv[e] * v4;
            __builtin_nontemporal_store(o4, (f32x4*)(op + (size_t)m * (8 * VD)));
        }
    }
}

extern "C" void kernel_launch(void* const* d_in, const int* in_sizes, int n_in,
                              void* d_out, int out_size, void* d_ws, size_t ws_size,
                              hipStream_t stream) {
    const float* q  = (const float*)d_in[0];
    const float* k  = (const float*)d_in[1];
    const float* v  = (const float*)d_in[2];
    const float* a  = (const float*)d_in[3];
    const float* b  = (const float*)d_in[4];
    const float* gk = (const float*)d_in[5];
    const float* h0 = (const float*)d_in[6];
    float* out = (float*)d_out;

    dplr_decode_colsplit_kernel<<<NBLK, 256, 0, stream>>>(q, k, v, a, b, gk, h0, out);
}

// Round 7
// 253.405 us; speedup vs baseline: 1.0053x; 1.0053x over previous
//
#include <hip/hip_runtime.h>

// RWKV-7 DPLR single-step decode: B=64, H=32, K=V=128, fp32.
// v8: FULL register keep + zero barriers. Rounds 1-6 eliminated
// occupancy (18-62%, no effect), barriers (zero-barrier same time),
// MLP (47% occ, no effect), and traffic volume (205-268MB, no effect)
// as limiters -- every structure lands at 83-92us. But no version yet
// combined minimum traffic (single h0 read) with free-running waves.
// v8: one wave per bh (v6 geometry), Hk[64] = the wave's entire 16KB
// H-slice held in 256 VGPRs (gfx950: 512-VGPR file, no spill to ~450,
// occupancy is grid-bound at 8 waves/CU regardless). Per wave:
//   issue 64 independent 1KB loads -> butterfly-reduce s/t ->
//   64 nt stores. H read ONCE, Ht written once, zero s_barrier.
// This is the decisive BW test: reads at 6.3 TB/s = 21us, even fully
// serial read-then-write = ~42us. If it still runs ~85us, the pattern
// is at its measured roofline.

#define KD 128
#define VD 128
#define BH_TOTAL 2048        // B*H
#define WPB 4                // waves per block (256 threads)
#define NBLK (BH_TOTAL/WPB)  // 512 blocks
#define NCHUNK 64            // 64 chunks x (2 rows x 128B) = 16KB per lane-half

typedef float f32x4 __attribute__((ext_vector_type(4)));

__global__ __launch_bounds__(256, 1) void dplr_decode_fullkeep_kernel(
    const float* __restrict__ q_,  const float* __restrict__ k_,
    const float* __restrict__ v_,  const float* __restrict__ a_,
    const float* __restrict__ b_,  const float* __restrict__ gk_,
    const float* __restrict__ h0_, float* __restrict__ out_)
{
    const int tid  = threadIdx.x;
    const int wid  = tid >> 6;           // wave in block, 0..3
    const int lane = tid & 63;
    const int bh   = blockIdx.x * WPB + wid;
    const int half = lane >> 5;          // 0: even rows, 1: odd rows
    const int c4   = (lane & 31) * 4;    // column base, 0..124

    const size_t vec_off = (size_t)bh * KD;
    const size_t h_off   = (size_t)bh * (KD * VD);

    // wave-private LDS tables, parity-split: value for row r=2m+p at [p][m]
    __shared__ float aL[WPB][2][64], qgL[WPB][2][64], gL[WPB][2][64],
                     bL[WPB][2][64], kL[WPB][2][64];

    // ---- issue ALL 64 H loads first (each lane: 16KB in flight) ----
    f32x4 Hk[NCHUNK];
    const float* hp = h0_ + h_off + (size_t)half * VD + c4;
#pragma unroll
    for (int m = 0; m < NCHUNK; ++m) {
        Hk[m] = *(const f32x4*)(hp + (size_t)m * 256);
    }

    // ---- stage per-(b,h) vectors while loads fly ----
    const float q_lo = q_[vec_off + lane],  q_hi = q_[vec_off + lane + 64];
    const float b_lo = b_[vec_off + lane],  b_hi = b_[vec_off + lane + 64];
    const float k_lo = k_[vec_off + lane],  k_hi = k_[vec_off + lane + 64];
    const float a_lo = a_[vec_off + lane],  a_hi = a_[vec_off + lane + 64];
    const float g_lo = expf(gk_[vec_off + lane]);
    const float g_hi = expf(gk_[vec_off + lane + 64]);

    {   // element i -> parity i&1, chunk i>>1 ; (i+64): same parity, chunk+32
        const int p  = lane & 1;
        const int m0 = lane >> 1;
        aL [wid][p][m0] = a_lo;        aL [wid][p][m0 + 32] = a_hi;
        qgL[wid][p][m0] = q_lo * g_lo; qgL[wid][p][m0 + 32] = q_hi * g_hi;
        gL [wid][p][m0] = g_lo;        gL [wid][p][m0 + 32] = g_hi;
        bL [wid][p][m0] = b_lo;        bL [wid][p][m0 + 32] = b_hi;
        kL [wid][p][m0] = k_lo;        kL [wid][p][m0 + 32] = k_hi;
    }

    // ---- alpha = q.b, beta = q.k : butterfly, all lanes get totals ----
    float alpha = q_lo * b_lo + q_hi * b_hi;
    float beta  = q_lo * k_lo + q_hi * k_hi;
#pragma unroll
    for (int o = 32; o > 0; o >>= 1) {
        alpha += __shfl_xor(alpha, o, 64);
        beta  += __shfl_xor(beta,  o, 64);
    }

    // v for my 4 columns
    const f32x4 v4 = *(const f32x4*)(v_ + vec_off + c4);

    // Pin all 64 chunks: forces one-time materialization in VGPRs
    // (round-1 lesson: without this the compiler rematerializes loads).
#pragma unroll
    for (int m = 0; m < NCHUNK; ++m) {
        asm volatile("" : "+v"(Hk[m]));
    }

    // ---- phase 1: s/t partials over my 64 rows (all from registers) ----
    f32x4 sp = {0.f, 0.f, 0.f, 0.f};
    f32x4 tp = {0.f, 0.f, 0.f, 0.f};
#pragma unroll
    for (int mb = 0; mb < NCHUNK / 4; ++mb) {
        const f32x4 av = *(const f32x4*)&aL [wid][half][mb * 4];
        const f32x4 qv = *(const f32x4*)&qgL[wid][half][mb * 4];
#pragma unroll
        for (int e = 0; e < 4; ++e) {
            sp += av[e] * Hk[mb * 4 + e];
            tp += qv[e] * Hk[mb * 4 + e];
        }
    }

    // ---- wave-local combine across parities (even+odd rows) ----
    f32x4 s4, t4;
#pragma unroll
    for (int e = 0; e < 4; ++e) {
        s4[e] = sp[e] + __shfl_xor(sp[e], 32, 64);
        t4[e] = tp[e] + __shfl_xor(tp[e], 32, 64);
    }

    // ---- o = t + alpha*s + beta*v (half 0 lanes cover cols 0..127) ----
    if (half == 0) {
        const f32x4 o4 = t4 + alpha * s4 + beta * v4;
        *(f32x4*)(out_ + (size_t)bh * VD + c4) = o4;
    }

    // ---- phase 2: Ht = g*H + b s^T + k v^T, straight from registers ----
    float* op = out_ + (size_t)BH_TOTAL * VD + h_off + (size_t)half * VD + c4;
#pragma unroll
    for (int mb = 0; mb < NCHUNK / 4; ++mb) {
        const f32x4 gv = *(const f32x4*)&gL[wid][half][mb * 4];
        const f32x4 bv = *(const f32x4*)&bL[wid][half][mb * 4];
        const f32x4 kv = *(const f32x4*)&kL[wid][half][mb * 4];
#pragma unroll
        for (int e = 0; e < 4; ++e) {
            const int m = mb * 4 + e;
            const f32x4 o4 = gv[e] * Hk[m] + bv[e] * s4 + kv[e] * v4;
            __builtin_nontemporal_store(o4, (f32x4*)(op + (size_t)m * 256));
        }
    }
}

extern "C" void kernel_launch(void* const* d_in, const int* in_sizes, int n_in,
                              void* d_out, int out_size, void* d_ws, size_t ws_size,
                              hipStream_t stream) {
    const float* q  = (const float*)d_in[0];
    const float* k  = (const float*)d_in[1];
    const float* v  = (const float*)d_in[2];
    const float* a  = (const float*)d_in[3];
    const float* b  = (const float*)d_in[4];
    const float* gk = (const float*)d_in[5];
    const float* h0 = (const float*)d_in[6];
    float* out = (float*)d_out;

    dplr_decode_fullkeep_kernel<<<NBLK, 256, 0, stream>>>(q, k, v, a, b, gk, h0, out);
}